// Round 12
// baseline (406.078 us; speedup 1.0000x reference)
//
#include <hip/hip_runtime.h>
#include <hip/hip_bf16.h>
#include <math.h>

#define B_   16
#define T_   4096
#define KD_  1024
#define AD_  512
#define VD_  1024

typedef float f32x4 __attribute__((ext_vector_type(4)));
typedef short s16x8 __attribute__((ext_vector_type(8)));

static __device__ __forceinline__ short f2bf(float f) {
    __hip_bfloat16 h = __float2bfloat16(f);
    return __builtin_bit_cast(short, h);
}

static __device__ __forceinline__ float fast_tanh(float x) {
    x = fminf(fmaxf(x, -15.f), 15.f);
    float e = __expf(2.f * x);
    return (e - 1.f) / (e + 1.f);
}

static __device__ __forceinline__ void gload16(const void* g, void* l) {
    __builtin_amdgcn_global_load_lds(
        (const __attribute__((address_space(1))) void*)(g),
        (__attribute__((address_space(3))) void*)(l), 16, 0, 0);
}

// Blocked operand layout, BK=32 (32 K-tiles), 256-row/col tiles (r9-verified):
//   keyB: [mt 256-rows][kt 32][chunk c 1024][8 bf16], c = (r<<2)|(sub^((r>>1)&3))
//   WkTB: [nt 256-cols][kt 32][chunk c 1024][8 bf16], same formula
// LDS stays linear (global_load_lds); ds_read applies the same XOR -> 2-way (free).

// ---------------- fused prep kernel: cvt(4096) | wtrans(1024) | qproj(256) | memset(144) ----------------
__global__ __launch_bounds__(256) void prep_kernel(
    const float* __restrict__ key, short* __restrict__ keyB,
    const float* __restrict__ Wk_mono, const float* __restrict__ Wk_chunk,
    short* __restrict__ WkTB,
    const float* __restrict__ query,
    const float* __restrict__ Wq_mono, const float* __restrict__ b_mono,
    const float* __restrict__ Wq_chunk, const float* __restrict__ b_chunk,
    float* __restrict__ qb,
    float* __restrict__ e_ws, float* __restrict__ outzero) {
    int bid = blockIdx.x;
    int tid = threadIdx.x;

    if (bid < 4096) {
        // ---- key f32 -> bf16, blocked+swizzled (r9 BK=32 layout) ----
        const size_t nchunk = (size_t)B_ * T_ * KD_ / 8;
        size_t stride = (size_t)4096 * 256;
        for (size_t g = (size_t)bid * 256 + tid; g < nchunk; g += stride) {
            const float* p = key + g * 8;
            f32x4 f0 = *reinterpret_cast<const f32x4*>(p);
            f32x4 f1 = *reinterpret_cast<const f32x4*>(p + 4);
            s16x8 h;
            h[0] = f2bf(f0[0]); h[1] = f2bf(f0[1]); h[2] = f2bf(f0[2]); h[3] = f2bf(f0[3]);
            h[4] = f2bf(f1[0]); h[5] = f2bf(f1[1]); h[6] = f2bf(f1[2]); h[7] = f2bf(f1[3]);
            size_t m = g >> 7;
            int kc = (int)(g & 127);
            size_t mt = m >> 8;
            int r = (int)(m & 255);
            int kt = kc >> 2;
            int sub = kc & 3;
            int c = (r << 2) | (sub ^ ((r >> 1) & 3));
            *reinterpret_cast<s16x8*>(keyB + (((mt * 32 + kt) * 1024 + c) << 3)) = h;
        }
    } else if (bid < 5120) {
        // ---- weights -> bf16 blocked+swizzled WkTB (r9 256-col layout) ----
        __shared__ float tile[32][33];
        int wbid = bid - 4096;
        int n0 = (wbid & 31) * 32;
        int k0 = (wbid >> 5) * 32;
        int tx = tid & 31;
        int ty = tid >> 5;
        const float* src;
        int nloc;
        if (n0 < 512) { src = Wk_mono;  nloc = n0; }
        else          { src = Wk_chunk; nloc = n0 - 512; }
#pragma unroll
        for (int i = 0; i < 4; ++i) {
            int k = ty + i * 8;
            tile[k][tx] = src[(size_t)(k0 + k) * AD_ + nloc + tx];
        }
        __syncthreads();
        if (tid < 128) {
            int rl = tid >> 2;
            int sub = tid & 3;
            s16x8 h;
#pragma unroll
            for (int j = 0; j < 8; ++j)
                h[j] = f2bf(tile[sub * 8 + j][rl]);
            int n = n0 + rl;
            int nt = n >> 8;
            int rloc = n & 255;
            int kt = k0 >> 5;
            int c = (rloc << 2) | (sub ^ ((rloc >> 1) & 3));
            *reinterpret_cast<s16x8*>(WkTB + (((size_t)(nt * 32 + kt) * 1024 + c) << 3)) = h;
        }
    } else if (bid < 5376) {
        // ---- qproj ----
        __shared__ float red[4][64];
        int qbid = bid - 5120;
        int b = qbid & 15;
        int mat = (qbid >> 4) & 1;
        int ac = qbid >> 5;
        const float* Wq = mat ? Wq_chunk : Wq_mono;
        const float* bb = mat ? b_chunk : b_mono;
        int al = tid & 63;
        int dg = tid >> 6;
        int a = ac * 64 + al;
        const float* q = query + b * KD_ + dg * 256;
        const float* wp = Wq + (size_t)(dg * 256) * AD_ + a;
        float s = 0.f;
#pragma unroll 4
        for (int d = 0; d < 256; ++d)
            s += q[d] * wp[(size_t)d * AD_];
        red[dg][al] = s;
        __syncthreads();
        if (dg == 0) {
            float t = red[0][al] + red[1][al] + red[2][al] + red[3][al];
            qb[(mat * B_ + b) * AD_ + a] = t + bb[a];
        }
    } else {
        // ---- zero e_ws (128 blocks x 4KB) then out (16 blocks x 4KB) ----
        int zbid = bid - 5376;
        f32x4 z = {0.f, 0.f, 0.f, 0.f};
        if (zbid < 128) {
            float* dst = e_ws + (size_t)zbid * 1024 + tid * 4;
            *reinterpret_cast<f32x4*>(dst) = z;
        } else {
            float* dst = outzero + (size_t)(zbid - 128) * 1024 + tid * 4;
            *reinterpret_cast<f32x4*>(dst) = z;
        }
    }
}

// ---------------- kernel 3: fused GEMM 256x256, 4 waves of 128x128 (LDS-BW-optimal), 2-phase dbuf ----------------
__global__ __launch_bounds__(256) void gemm_e_kernel(
    const short* __restrict__ keyB,
    const short* __restrict__ WkTB,
    const float* __restrict__ qb,
    const float* __restrict__ v_mono, const float* __restrict__ v_chunk,
    float* __restrict__ e_ws /* [2][B_*T_] */) {
    __shared__ short As[2][1024 * 8];   // 2 x 16 KB
    __shared__ short Bs[2][1024 * 8];   // 2 x 16 KB
    int tid = threadIdx.x;
    int bid = blockIdx.x;
    int swz = (bid & 7) * 128 + (bid >> 3);   // XCD-aware (1024 % 8 == 0, bijective)
    int mt = swz >> 2;                        // 0..255
    int nt = swz & 3;                         // 0..3
    int mBase = mt * 256;
    int nBase = nt * 256;
    int lane = tid & 63;
    int wid = tid >> 6;                       // 0..3
    int wr = wid >> 1, wc = wid & 1;          // 2x2 waves, each 128x128
    int col16 = lane & 15, g4 = lane >> 4;

    // staging: thread stages 4 A chunks + 4 B chunks (linear LDS dest)
    const short* pA[4];
    const short* pB[4];
    int sOff[4];
#pragma unroll
    for (int i = 0; i < 4; ++i) {
        pA[i] = keyB + ((size_t)mt * 32 * 1024 + i * 256 + tid) * 8;
        pB[i] = WkTB + ((size_t)nt * 32 * 1024 + i * 256 + tid) * 8;
        sOff[i] = (i * 256 + wid * 64) * 8;
    }

    // loop-invariant swizzled ds_read offsets (shorts)
    int aoff[8], boff[8];
#pragma unroll
    for (int fi = 0; fi < 8; ++fi) {
        int row = wr * 128 + fi * 16 + col16;          // 0..255
        aoff[fi] = (row * 4 + (g4 ^ ((row >> 1) & 3))) * 8;
    }
#pragma unroll
    for (int fj = 0; fj < 8; ++fj) {
        int coln = wc * 128 + fj * 16 + col16;         // 0..255
        boff[fj] = (coln * 4 + (g4 ^ ((coln >> 1) & 3))) * 8;
    }

    f32x4 acc[8][8];
#pragma unroll
    for (int i = 0; i < 8; ++i)
#pragma unroll
        for (int j = 0; j < 8; ++j) acc[i][j] = (f32x4){0.f, 0.f, 0.f, 0.f};

    // prologue: stage tile 0 into buf 0
#pragma unroll
    for (int i = 0; i < 4; ++i) {
        gload16(pA[i], &As[0][sOff[i]]);
        gload16(pB[i], &Bs[0][sOff[i]]);
        pA[i] += 8192; pB[i] += 8192;
    }
    __syncthreads();

    int cur = 0;
    for (int kt = 0; kt < 31; ++kt) {
        int nxt = cur ^ 1;
        // prefetch next tile (overlaps with MFMA; drained by the barrier)
#pragma unroll
        for (int i = 0; i < 4; ++i) {
            gload16(pA[i], &As[nxt][sOff[i]]);
            gload16(pB[i], &Bs[nxt][sOff[i]]);
            pA[i] += 8192; pB[i] += 8192;
        }
        // compute current tile: 8x8 frags per wave
        s16x8 bfr[8];
#pragma unroll
        for (int fj = 0; fj < 8; ++fj)
            bfr[fj] = *reinterpret_cast<const s16x8*>(&Bs[cur][boff[fj]]);
#pragma unroll
        for (int fi = 0; fi < 8; ++fi) {
            s16x8 af = *reinterpret_cast<const s16x8*>(&As[cur][aoff[fi]]);
#pragma unroll
            for (int fj = 0; fj < 8; ++fj)
                acc[fi][fj] = __builtin_amdgcn_mfma_f32_16x16x32_bf16(af, bfr[fj], acc[fi][fj], 0, 0, 0);
        }
        __syncthreads();   // vmcnt drain: next buffer published, cur free
        cur = nxt;
    }
    {   // final tile
        s16x8 bfr[8];
#pragma unroll
        for (int fj = 0; fj < 8; ++fj)
            bfr[fj] = *reinterpret_cast<const s16x8*>(&Bs[cur][boff[fj]]);
#pragma unroll
        for (int fi = 0; fi < 8; ++fi) {
            s16x8 af = *reinterpret_cast<const s16x8*>(&As[cur][aoff[fi]]);
#pragma unroll
            for (int fj = 0; fj < 8; ++fj)
                acc[fi][fj] = __builtin_amdgcn_mfma_f32_16x16x32_bf16(af, bfr[fj], acc[fi][fj], 0, 0, 0);
        }
    }

    // epilogue: e[row] += sum_a v[a] * tanh(C[row][a] + qb[b][a])
    int bIdx = mBase >> 12;
    int matrix = nBase >> 9;            // nt 0,1 -> mono; 2,3 -> chunk
    int aBase = (nBase & 511) + wc * 128 + col16;
    const float* qbRow = qb + (matrix * B_ + bIdx) * AD_;
    const float* vv = matrix ? v_chunk : v_mono;
    float* eArr = e_ws + matrix * (B_ * T_);
    float qcol[8], vcol[8];
#pragma unroll
    for (int fj = 0; fj < 8; ++fj) {
        int a = aBase + fj * 16;
        qcol[fj] = qbRow[a];
        vcol[fj] = vv[a];
    }
#pragma unroll
    for (int fi = 0; fi < 8; ++fi) {
        float s0 = 0.f, s1 = 0.f, s2 = 0.f, s3 = 0.f;
#pragma unroll
        for (int fj = 0; fj < 8; ++fj) {
            s0 += fast_tanh(acc[fi][fj][0] + qcol[fj]) * vcol[fj];
            s1 += fast_tanh(acc[fi][fj][1] + qcol[fj]) * vcol[fj];
            s2 += fast_tanh(acc[fi][fj][2] + qcol[fj]) * vcol[fj];
            s3 += fast_tanh(acc[fi][fj][3] + qcol[fj]) * vcol[fj];
        }
#pragma unroll
        for (int mask = 1; mask < 16; mask <<= 1) {
            s0 += __shfl_xor(s0, mask, 64);
            s1 += __shfl_xor(s1, mask, 64);
            s2 += __shfl_xor(s2, mask, 64);
            s3 += __shfl_xor(s3, mask, 64);
        }
        if (col16 == 0) {
            int rowB = mBase + wr * 128 + fi * 16 + g4 * 4;
            atomicAdd(&eArr[rowB + 0], s0);
            atomicAdd(&eArr[rowB + 1], s1);
            atomicAdd(&eArr[rowB + 2], s2);
            atomicAdd(&eArr[rowB + 3], s3);
        }
    }
}

// ---------------- kernel 4: per-batch scan -> aw, beta ----------------
__global__ __launch_bounds__(256) void scan_kernel(
    const float* __restrict__ e_ws,
    const float* __restrict__ noise,
    const float* __restrict__ r_mono, const float* __restrict__ r_chunk,
    float* __restrict__ aw_out, float* __restrict__ beta_out) {
    __shared__ float s_aw[T_];
    __shared__ float s_sexp[T_];
    __shared__ float s_ad[T_];
    __shared__ float s_w[4];
    int b = blockIdx.x;
    int tid = threadIdx.x;
    int lane = tid & 63;
    int wid4 = tid >> 6;
    int t0 = tid * 16;
    const float* em = e_ws + b * T_;
    const float* ec = e_ws + B_ * T_ + b * T_;
    const float* nz = noise + b * T_;
    float rm = r_mono[0], rc = r_chunk[0];

    float pv[16], lp[16];
    float run = 0.f;
#pragma unroll
    for (int j = 0; j < 16; ++j) {
        float x = em[t0 + j] + rm + nz[t0 + j];
        float p = 1.f / (1.f + expf(-x));
        pv[j] = p;
        float om = fminf(fmaxf(1.f - p, 1e-10f), 1.f);
        lp[j] = run;
        run += logf(om);
    }
    float x = run;
#pragma unroll
    for (int off = 1; off < 64; off <<= 1) {
        float y = __shfl_up(x, off, 64);
        if (lane >= off) x += y;
    }
    if (lane == 63) s_w[wid4] = x;
    __syncthreads();
    float wbase = 0.f;
#pragma unroll
    for (int i = 0; i < 3; ++i) if (i < wid4) wbase += s_w[i];
    float base = 1.f + (wbase + x - run);
#pragma unroll
    for (int j = 0; j < 16; ++j) {
        float aw = pv[j] * expf(base + lp[j]);
        s_aw[t0 + j] = aw;
        aw_out[b * T_ + t0 + j] = aw;
    }
    float evs[16];
    float lmax = -INFINITY;
#pragma unroll
    for (int j = 0; j < 16; ++j) {
        float v = ec[t0 + j] + rc;
        evs[j] = v;
        lmax = fmaxf(lmax, v);
    }
#pragma unroll
    for (int off = 1; off < 64; off <<= 1)
        lmax = fmaxf(lmax, __shfl_xor(lmax, off, 64));
    __syncthreads();
    if (lane == 0) s_w[wid4] = lmax;
    __syncthreads();
    float mx = fmaxf(fmaxf(s_w[0], s_w[1]), fmaxf(s_w[2], s_w[3]));
#pragma unroll
    for (int j = 0; j < 16; ++j)
        s_sexp[t0 + j] = fmaxf(expf(evs[j] - mx), 1e-5f);
    __syncthreads();
#pragma unroll
    for (int j = 0; j < 16; ++j) {
        int t = t0 + j;
        int lo = t - 7; if (lo < 0) lo = 0;
        float d = 0.f;
        for (int i = lo; i <= t; ++i) d += s_sexp[i];
        s_ad[t] = s_aw[t] / d;
    }
    __syncthreads();
#pragma unroll
    for (int j = 0; j < 16; ++j) {
        int t = t0 + j;
        int hi = t + 7; if (hi > T_ - 1) hi = T_ - 1;
        float m2 = 0.f;
        for (int i = t; i <= hi; ++i) m2 += s_ad[i];
        beta_out[b * T_ + t] = s_sexp[t] * m2;
    }
}

// ---------------- kernel 5: cv[b][d] = sum_t beta[b][t]*value[b][t][d] ----------------
__global__ __launch_bounds__(256) void cv_kernel(
    const float* __restrict__ value,
    const float* __restrict__ beta,
    float* __restrict__ cv) {
    __shared__ float s_beta[128];
    int b = blockIdx.x;
    int tc = blockIdx.y;
    int tid = threadIdx.x;
    int t0 = tc * 128;
    if (tid < 128) s_beta[tid] = beta[b * T_ + t0 + tid];
    __syncthreads();
    int d0 = tid * 4;
    f32x4 acc = {0.f, 0.f, 0.f, 0.f};
    const float* vp = value + (size_t)(b * T_ + t0) * VD_ + d0;
#pragma unroll 4
    for (int i = 0; i < 128; ++i) {
        f32x4 v = *reinterpret_cast<const f32x4*>(vp + (size_t)i * VD_);
        float bt = s_beta[i];
        acc[0] += bt * v[0];
        acc[1] += bt * v[1];
        acc[2] += bt * v[2];
        acc[3] += bt * v[3];
    }
    atomicAdd(&cv[b * VD_ + d0 + 0], acc[0]);
    atomicAdd(&cv[b * VD_ + d0 + 1], acc[1]);
    atomicAdd(&cv[b * VD_ + d0 + 2], acc[2]);
    atomicAdd(&cv[b * VD_ + d0 + 3], acc[3]);
}

extern "C" void kernel_launch(void* const* d_in, const int* in_sizes, int n_in,
                              void* d_out, int out_size, void* d_ws, size_t ws_size,
                              hipStream_t stream) {
    const float* key      = (const float*)d_in[0];
    const float* value    = (const float*)d_in[1];
    const float* query    = (const float*)d_in[2];
    const float* noise    = (const float*)d_in[3];
    const float* Wk_mono  = (const float*)d_in[4];
    const float* b_mono   = (const float*)d_in[5];
    const float* Wq_mono  = (const float*)d_in[6];
    const float* Wk_chunk = (const float*)d_in[7];
    const float* b_chunk  = (const float*)d_in[8];
    const float* Wq_chunk = (const float*)d_in[9];
    const float* r_mono   = (const float*)d_in[10];
    const float* r_chunk  = (const float*)d_in[11];
    const float* v_mono   = (const float*)d_in[12];
    const float* v_chunk  = (const float*)d_in[13];
    float* out = (float*)d_out;   // [0,16384): cv ; [16384, 81920): aw

    char* ws = (char*)d_ws;
    size_t off = 0;
    float* e_ws = (float*)(ws + off); off += 2 * B_ * T_ * sizeof(float);      // 512 KB
    float* qb   = (float*)(ws + off); off += 2 * B_ * AD_ * sizeof(float);     // 64 KB
    short* WkTB = (short*)(ws + off); off += (size_t)KD_ * KD_ * 2;            // 2 MB
    float* beta = (float*)(ws + off); off += B_ * T_ * sizeof(float);          // 256 KB
    short* keyB = (short*)(ws + off);                                          // 134 MB

    prep_kernel<<<5520, 256, 0, stream>>>(key, keyB, Wk_mono, Wk_chunk, WkTB,
                                          query, Wq_mono, b_mono, Wq_chunk, b_chunk, qb,
                                          e_ws, out);
    gemm_e_kernel<<<1024, 256, 0, stream>>>(keyB, WkTB, qb, v_mono, v_chunk, e_ws);
    scan_kernel<<<16, 256, 0, stream>>>(e_ws, noise, r_mono, r_chunk, out + B_ * VD_, beta);
    cv_kernel<<<dim3(16, 32), 256, 0, stream>>>(value, beta, out);
}

// Round 13
// 401.977 us; speedup vs baseline: 1.0102x; 1.0102x over previous
//
#include <hip/hip_runtime.h>
#include <hip/hip_bf16.h>
#include <math.h>

#define B_   16
#define T_   4096
#define KD_  1024
#define AD_  512
#define VD_  1024

typedef float f32x4 __attribute__((ext_vector_type(4)));
typedef short s16x8 __attribute__((ext_vector_type(8)));

static __device__ __forceinline__ short f2bf(float f) {
    __hip_bfloat16 h = __float2bfloat16(f);
    return __builtin_bit_cast(short, h);
}

static __device__ __forceinline__ float fast_tanh(float x) {
    x = fminf(fmaxf(x, -15.f), 15.f);
    float e = __expf(2.f * x);
    return (e - 1.f) / (e + 1.f);
}

static __device__ __forceinline__ void gload16(const void* g, void* l) {
    __builtin_amdgcn_global_load_lds(
        (const __attribute__((address_space(1))) void*)(g),
        (__attribute__((address_space(3))) void*)(l), 16, 0, 0);
}

// Blocked operand layout, BK=32 (32 K-tiles), 256-row/col tiles (r9-verified):
//   keyB: [mt 256-rows][kt 32][chunk c 1024][8 bf16], c = (r<<2)|(sub^((r>>1)&3))
//   WkTB: [nt 256-cols][kt 32][chunk c 1024][8 bf16], same formula
// LDS stays linear (global_load_lds); ds_read applies the same XOR -> 2-way (free).

// ---------------- fused prep kernel: cvt(4096) | wtrans(1024) | qproj(256) | memset(144) ----------------
__global__ __launch_bounds__(256) void prep_kernel(
    const float* __restrict__ key, short* __restrict__ keyB,
    const float* __restrict__ Wk_mono, const float* __restrict__ Wk_chunk,
    short* __restrict__ WkTB,
    const float* __restrict__ query,
    const float* __restrict__ Wq_mono, const float* __restrict__ b_mono,
    const float* __restrict__ Wq_chunk, const float* __restrict__ b_chunk,
    float* __restrict__ qb,
    float* __restrict__ e_ws, float* __restrict__ outzero) {
    int bid = blockIdx.x;
    int tid = threadIdx.x;

    if (bid < 4096) {
        // ---- key f32 -> bf16, blocked+swizzled ----
        const size_t nchunk = (size_t)B_ * T_ * KD_ / 8;
        size_t stride = (size_t)4096 * 256;
        for (size_t g = (size_t)bid * 256 + tid; g < nchunk; g += stride) {
            const float* p = key + g * 8;
            f32x4 f0 = *reinterpret_cast<const f32x4*>(p);
            f32x4 f1 = *reinterpret_cast<const f32x4*>(p + 4);
            s16x8 h;
            h[0] = f2bf(f0[0]); h[1] = f2bf(f0[1]); h[2] = f2bf(f0[2]); h[3] = f2bf(f0[3]);
            h[4] = f2bf(f1[0]); h[5] = f2bf(f1[1]); h[6] = f2bf(f1[2]); h[7] = f2bf(f1[3]);
            size_t m = g >> 7;
            int kc = (int)(g & 127);
            size_t mt = m >> 8;
            int r = (int)(m & 255);
            int kt = kc >> 2;
            int sub = kc & 3;
            int c = (r << 2) | (sub ^ ((r >> 1) & 3));
            *reinterpret_cast<s16x8*>(keyB + (((mt * 32 + kt) * 1024 + c) << 3)) = h;
        }
    } else if (bid < 5120) {
        // ---- weights -> bf16 blocked+swizzled WkTB ----
        __shared__ float tile[32][33];
        int wbid = bid - 4096;
        int n0 = (wbid & 31) * 32;
        int k0 = (wbid >> 5) * 32;
        int tx = tid & 31;
        int ty = tid >> 5;
        const float* src;
        int nloc;
        if (n0 < 512) { src = Wk_mono;  nloc = n0; }
        else          { src = Wk_chunk; nloc = n0 - 512; }
#pragma unroll
        for (int i = 0; i < 4; ++i) {
            int k = ty + i * 8;
            tile[k][tx] = src[(size_t)(k0 + k) * AD_ + nloc + tx];
        }
        __syncthreads();
        if (tid < 128) {
            int rl = tid >> 2;
            int sub = tid & 3;
            s16x8 h;
#pragma unroll
            for (int j = 0; j < 8; ++j)
                h[j] = f2bf(tile[sub * 8 + j][rl]);
            int n = n0 + rl;
            int nt = n >> 8;
            int rloc = n & 255;
            int kt = k0 >> 5;
            int c = (rloc << 2) | (sub ^ ((rloc >> 1) & 3));
            *reinterpret_cast<s16x8*>(WkTB + (((size_t)(nt * 32 + kt) * 1024 + c) << 3)) = h;
        }
    } else if (bid < 5376) {
        // ---- qproj ----
        __shared__ float red[4][64];
        int qbid = bid - 5120;
        int b = qbid & 15;
        int mat = (qbid >> 4) & 1;
        int ac = qbid >> 5;
        const float* Wq = mat ? Wq_chunk : Wq_mono;
        const float* bb = mat ? b_chunk : b_mono;
        int al = tid & 63;
        int dg = tid >> 6;
        int a = ac * 64 + al;
        const float* q = query + b * KD_ + dg * 256;
        const float* wp = Wq + (size_t)(dg * 256) * AD_ + a;
        float s = 0.f;
#pragma unroll 4
        for (int d = 0; d < 256; ++d)
            s += q[d] * wp[(size_t)d * AD_];
        red[dg][al] = s;
        __syncthreads();
        if (dg == 0) {
            float t = red[0][al] + red[1][al] + red[2][al] + red[3][al];
            qb[(mat * B_ + b) * AD_ + a] = t + bb[a];
        }
    } else {
        // ---- zero e_ws (128 blocks x 4KB) then out (16 blocks x 4KB) ----
        int zbid = bid - 5376;
        f32x4 z = {0.f, 0.f, 0.f, 0.f};
        if (zbid < 128) {
            float* dst = e_ws + (size_t)zbid * 1024 + tid * 4;
            *reinterpret_cast<f32x4*>(dst) = z;
        } else {
            float* dst = outzero + (size_t)(zbid - 128) * 1024 + tid * 4;
            *reinterpret_cast<f32x4*>(dst) = z;
        }
    }
}

// ---------------- kernel 3: fused GEMM 256x256, 4 waves of 128x128, 3-buf depth-2 counted vmcnt ----------------
__global__ __launch_bounds__(256, 1) void gemm_e_kernel(
    const short* __restrict__ keyB,
    const short* __restrict__ WkTB,
    const float* __restrict__ qb,
    const float* __restrict__ v_mono, const float* __restrict__ v_chunk,
    float* __restrict__ e_ws /* [2][B_*T_] */) {
    __shared__ short As[3][1024 * 8];   // 3 x 16 KB
    __shared__ short Bs[3][1024 * 8];   // 3 x 16 KB
    int tid = threadIdx.x;
    int bid = blockIdx.x;
    int swz = (bid & 7) * 128 + (bid >> 3);   // XCD-aware (1024 % 8 == 0, bijective)
    int mt = swz >> 2;                        // 0..255
    int nt = swz & 3;                         // 0..3
    int mBase = mt * 256;
    int nBase = nt * 256;
    int lane = tid & 63;
    int wid = tid >> 6;                       // 0..3
    int wr = wid >> 1, wc = wid & 1;          // 2x2 waves, each 128x128
    int col16 = lane & 15, g4 = lane >> 4;

    const short* aT = keyB + ((size_t)mt * 32 * 1024) * 8;
    const short* bT = WkTB + ((size_t)nt * 32 * 1024) * 8;
    int sOff[4];
#pragma unroll
    for (int i = 0; i < 4; ++i) sOff[i] = (i * 256 + wid * 64) * 8;

    auto stage = [&](int buf, int kt) {
#pragma unroll
        for (int i = 0; i < 4; ++i) {
            gload16(aT + ((size_t)kt * 1024 + i * 256 + tid) * 8, &As[buf][sOff[i]]);
            gload16(bT + ((size_t)kt * 1024 + i * 256 + tid) * 8, &Bs[buf][sOff[i]]);
        }
    };

    // loop-invariant swizzled ds_read offsets (shorts)
    int aoff[8], boff[8];
#pragma unroll
    for (int fi = 0; fi < 8; ++fi) {
        int row = wr * 128 + fi * 16 + col16;          // 0..255
        aoff[fi] = (row * 4 + (g4 ^ ((row >> 1) & 3))) * 8;
    }
#pragma unroll
    for (int fj = 0; fj < 8; ++fj) {
        int coln = wc * 128 + fj * 16 + col16;         // 0..255
        boff[fj] = (coln * 4 + (g4 ^ ((coln >> 1) & 3))) * 8;
    }

    f32x4 acc[8][8];
#pragma unroll
    for (int i = 0; i < 8; ++i)
#pragma unroll
        for (int j = 0; j < 8; ++j) acc[i][j] = (f32x4){0.f, 0.f, 0.f, 0.f};

    // prologue: stage tiles 0,1 (16 loads/thread in flight)
    stage(0, 0);
    stage(1, 1);

    int cur = 0;
    for (int kt = 0; kt < 31; ++kt) {
        // drain tile kt's 8 loads; tile kt+1's 8 stay in flight across the barrier
        asm volatile("s_waitcnt vmcnt(8)" ::: "memory");
        __builtin_amdgcn_s_barrier();
        asm volatile("" ::: "memory");
        if (kt < 30) {
            int pb = cur + 2; if (pb >= 3) pb -= 3;
            stage(pb, kt + 2);
        }
        // compute current tile: 8x8 frags per wave
        s16x8 bfr[8];
#pragma unroll
        for (int fj = 0; fj < 8; ++fj)
            bfr[fj] = *reinterpret_cast<const s16x8*>(&Bs[cur][boff[fj]]);
#pragma unroll
        for (int fi = 0; fi < 8; ++fi) {
            s16x8 af = *reinterpret_cast<const s16x8*>(&As[cur][aoff[fi]]);
#pragma unroll
            for (int fj = 0; fj < 8; ++fj)
                acc[fi][fj] = __builtin_amdgcn_mfma_f32_16x16x32_bf16(af, bfr[fj], acc[fi][fj], 0, 0, 0);
        }
        ++cur; if (cur == 3) cur = 0;
    }
    {   // final tile (kt = 31, buf = 31 % 3 = 1 = cur)
        asm volatile("s_waitcnt vmcnt(0)" ::: "memory");
        __builtin_amdgcn_s_barrier();
        asm volatile("" ::: "memory");
        s16x8 bfr[8];
#pragma unroll
        for (int fj = 0; fj < 8; ++fj)
            bfr[fj] = *reinterpret_cast<const s16x8*>(&Bs[cur][boff[fj]]);
#pragma unroll
        for (int fi = 0; fi < 8; ++fi) {
            s16x8 af = *reinterpret_cast<const s16x8*>(&As[cur][aoff[fi]]);
#pragma unroll
            for (int fj = 0; fj < 8; ++fj)
                acc[fi][fj] = __builtin_amdgcn_mfma_f32_16x16x32_bf16(af, bfr[fj], acc[fi][fj], 0, 0, 0);
        }
    }

    // epilogue: e[row] += sum_a v[a] * tanh(C[row][a] + qb[b][a])
    int bIdx = mBase >> 12;
    int matrix = nBase >> 9;            // nt 0,1 -> mono; 2,3 -> chunk
    int aBase = (nBase & 511) + wc * 128 + col16;
    const float* qbRow = qb + (matrix * B_ + bIdx) * AD_;
    const float* vv = matrix ? v_chunk : v_mono;
    float* eArr = e_ws + matrix * (B_ * T_);
    float qcol[8], vcol[8];
#pragma unroll
    for (int fj = 0; fj < 8; ++fj) {
        int a = aBase + fj * 16;
        qcol[fj] = qbRow[a];
        vcol[fj] = vv[a];
    }
#pragma unroll
    for (int fi = 0; fi < 8; ++fi) {
        float s0 = 0.f, s1 = 0.f, s2 = 0.f, s3 = 0.f;
#pragma unroll
        for (int fj = 0; fj < 8; ++fj) {
            s0 += fast_tanh(acc[fi][fj][0] + qcol[fj]) * vcol[fj];
            s1 += fast_tanh(acc[fi][fj][1] + qcol[fj]) * vcol[fj];
            s2 += fast_tanh(acc[fi][fj][2] + qcol[fj]) * vcol[fj];
            s3 += fast_tanh(acc[fi][fj][3] + qcol[fj]) * vcol[fj];
        }
#pragma unroll
        for (int mask = 1; mask < 16; mask <<= 1) {
            s0 += __shfl_xor(s0, mask, 64);
            s1 += __shfl_xor(s1, mask, 64);
            s2 += __shfl_xor(s2, mask, 64);
            s3 += __shfl_xor(s3, mask, 64);
        }
        if (col16 == 0) {
            int rowB = mBase + wr * 128 + fi * 16 + g4 * 4;
            atomicAdd(&eArr[rowB + 0], s0);
            atomicAdd(&eArr[rowB + 1], s1);
            atomicAdd(&eArr[rowB + 2], s2);
            atomicAdd(&eArr[rowB + 3], s3);
        }
    }
}

// ---------------- kernel 4: per-batch scan -> aw, beta ----------------
__global__ __launch_bounds__(256) void scan_kernel(
    const float* __restrict__ e_ws,
    const float* __restrict__ noise,
    const float* __restrict__ r_mono, const float* __restrict__ r_chunk,
    float* __restrict__ aw_out, float* __restrict__ beta_out) {
    __shared__ float s_aw[T_];
    __shared__ float s_sexp[T_];
    __shared__ float s_ad[T_];
    __shared__ float s_w[4];
    int b = blockIdx.x;
    int tid = threadIdx.x;
    int lane = tid & 63;
    int wid4 = tid >> 6;
    int t0 = tid * 16;
    const float* em = e_ws + b * T_;
    const float* ec = e_ws + B_ * T_ + b * T_;
    const float* nz = noise + b * T_;
    float rm = r_mono[0], rc = r_chunk[0];

    float pv[16], lp[16];
    float run = 0.f;
#pragma unroll
    for (int j = 0; j < 16; ++j) {
        float x = em[t0 + j] + rm + nz[t0 + j];
        float p = 1.f / (1.f + expf(-x));
        pv[j] = p;
        float om = fminf(fmaxf(1.f - p, 1e-10f), 1.f);
        lp[j] = run;
        run += logf(om);
    }
    float x = run;
#pragma unroll
    for (int off = 1; off < 64; off <<= 1) {
        float y = __shfl_up(x, off, 64);
        if (lane >= off) x += y;
    }
    if (lane == 63) s_w[wid4] = x;
    __syncthreads();
    float wbase = 0.f;
#pragma unroll
    for (int i = 0; i < 3; ++i) if (i < wid4) wbase += s_w[i];
    float base = 1.f + (wbase + x - run);
#pragma unroll
    for (int j = 0; j < 16; ++j) {
        float aw = pv[j] * expf(base + lp[j]);
        s_aw[t0 + j] = aw;
        aw_out[b * T_ + t0 + j] = aw;
    }
    float evs[16];
    float lmax = -INFINITY;
#pragma unroll
    for (int j = 0; j < 16; ++j) {
        float v = ec[t0 + j] + rc;
        evs[j] = v;
        lmax = fmaxf(lmax, v);
    }
#pragma unroll
    for (int off = 1; off < 64; off <<= 1)
        lmax = fmaxf(lmax, __shfl_xor(lmax, off, 64));
    __syncthreads();
    if (lane == 0) s_w[wid4] = lmax;
    __syncthreads();
    float mx = fmaxf(fmaxf(s_w[0], s_w[1]), fmaxf(s_w[2], s_w[3]));
#pragma unroll
    for (int j = 0; j < 16; ++j)
        s_sexp[t0 + j] = fmaxf(expf(evs[j] - mx), 1e-5f);
    __syncthreads();
#pragma unroll
    for (int j = 0; j < 16; ++j) {
        int t = t0 + j;
        int lo = t - 7; if (lo < 0) lo = 0;
        float d = 0.f;
        for (int i = lo; i <= t; ++i) d += s_sexp[i];
        s_ad[t] = s_aw[t] / d;
    }
    __syncthreads();
#pragma unroll
    for (int j = 0; j < 16; ++j) {
        int t = t0 + j;
        int hi = t + 7; if (hi > T_ - 1) hi = T_ - 1;
        float m2 = 0.f;
        for (int i = t; i <= hi; ++i) m2 += s_ad[i];
        beta_out[b * T_ + t] = s_sexp[t] * m2;
    }
}

// ---------------- kernel 5: cv[b][d] = sum_t beta[b][t]*value[b][t][d] ----------------
__global__ __launch_bounds__(256) void cv_kernel(
    const float* __restrict__ value,
    const float* __restrict__ beta,
    float* __restrict__ cv) {
    __shared__ float s_beta[128];
    int b = blockIdx.x;
    int tc = blockIdx.y;
    int tid = threadIdx.x;
    int t0 = tc * 128;
    if (tid < 128) s_beta[tid] = beta[b * T_ + t0 + tid];
    __syncthreads();
    int d0 = tid * 4;
    f32x4 acc = {0.f, 0.f, 0.f, 0.f};
    const float* vp = value + (size_t)(b * T_ + t0) * VD_ + d0;
#pragma unroll 4
    for (int i = 0; i < 128; ++i) {
        f32x4 v = *reinterpret_cast<const f32x4*>(vp + (size_t)i * VD_);
        float bt = s_beta[i];
        acc[0] += bt * v[0];
        acc[1] += bt * v[1];
        acc[2] += bt * v[2];
        acc[3] += bt * v[3];
    }
    atomicAdd(&cv[b * VD_ + d0 + 0], acc[0]);
    atomicAdd(&cv[b * VD_ + d0 + 1], acc[1]);
    atomicAdd(&cv[b * VD_ + d0 + 2], acc[2]);
    atomicAdd(&cv[b * VD_ + d0 + 3], acc[3]);
}

extern "C" void kernel_launch(void* const* d_in, const int* in_sizes, int n_in,
                              void* d_out, int out_size, void* d_ws, size_t ws_size,
                              hipStream_t stream) {
    const float* key      = (const float*)d_in[0];
    const float* value    = (const float*)d_in[1];
    const float* query    = (const float*)d_in[2];
    const float* noise    = (const float*)d_in[3];
    const float* Wk_mono  = (const float*)d_in[4];
    const float* b_mono   = (const float*)d_in[5];
    const float* Wq_mono  = (const float*)d_in[6];
    const float* Wk_chunk = (const float*)d_in[7];
    const float* b_chunk  = (const float*)d_in[8];
    const float* Wq_chunk = (const float*)d_in[9];
    const float* r_mono   = (const float*)d_in[10];
    const float* r_chunk  = (const float*)d_in[11];
    const float* v_mono   = (const float*)d_in[12];
    const float* v_chunk  = (const float*)d_in[13];
    float* out = (float*)d_out;   // [0,16384): cv ; [16384, 81920): aw

    char* ws = (char*)d_ws;
    size_t off = 0;
    float* e_ws = (float*)(ws + off); off += 2 * B_ * T_ * sizeof(float);      // 512 KB
    float* qb   = (float*)(ws + off); off += 2 * B_ * AD_ * sizeof(float);     // 64 KB
    short* WkTB = (short*)(ws + off); off += (size_t)KD_ * KD_ * 2;            // 2 MB
    float* beta = (float*)(ws + off); off += B_ * T_ * sizeof(float);          // 256 KB
    short* keyB = (short*)(ws + off);                                          // 134 MB

    prep_kernel<<<5520, 256, 0, stream>>>(key, keyB, Wk_mono, Wk_chunk, WkTB,
                                          query, Wq_mono, b_mono, Wq_chunk, b_chunk, qb,
                                          e_ws, out);
    gemm_e_kernel<<<1024, 256, 0, stream>>>(keyB, WkTB, qb, v_mono, v_chunk, e_ws);
    scan_kernel<<<16, 256, 0, stream>>>(e_ws, noise, r_mono, r_chunk, out + B_ * VD_, beta);
    cv_kernel<<<dim3(16, 32), 256, 0, stream>>>(value, beta, out);
}

// Round 14
// 336.567 us; speedup vs baseline: 1.2065x; 1.1943x over previous
//
#include <hip/hip_runtime.h>
#include <hip/hip_bf16.h>
#include <math.h>

#define B_   16
#define T_   4096
#define KD_  1024
#define AD_  512
#define VD_  1024

typedef float f32x4 __attribute__((ext_vector_type(4)));
typedef short s16x8 __attribute__((ext_vector_type(8)));

static __device__ __forceinline__ short f2bf(float f) {
    __hip_bfloat16 h = __float2bfloat16(f);
    return __builtin_bit_cast(short, h);
}

static __device__ __forceinline__ float fast_tanh(float x) {
    x = fminf(fmaxf(x, -15.f), 15.f);
    float e = __expf(2.f * x);
    return (e - 1.f) / (e + 1.f);
}

static __device__ __forceinline__ void gload16(const void* g, void* l) {
    __builtin_amdgcn_global_load_lds(
        (const __attribute__((address_space(1))) void*)(g),
        (__attribute__((address_space(3))) void*)(l), 16, 0, 0);
}

// Blocked operand layout, BK=64 K-tiles (16 of them), 256-row/col tiles:
//   keyB: [mt 256-rows][ktile 16][chunk c 2048][8 bf16], c = (r<<3)|(sub^(r&7)), r 0..255, sub 0..7
//   WkTB: [nt 256-cols][ktile 16][chunk c 2048][8 bf16], same formula
// LDS stays linear (global_load_lds); ds_read applies the same XOR -> 2-way (free).

// ---------------- fused prep kernel: cvt(4096) | wtrans(1024) | qproj(256) | memset(144) ----------------
__global__ __launch_bounds__(256) void prep_kernel(
    const float* __restrict__ key, short* __restrict__ keyB,
    const float* __restrict__ Wk_mono, const float* __restrict__ Wk_chunk,
    short* __restrict__ WkTB,
    const float* __restrict__ query,
    const float* __restrict__ Wq_mono, const float* __restrict__ b_mono,
    const float* __restrict__ Wq_chunk, const float* __restrict__ b_chunk,
    float* __restrict__ qb,
    float* __restrict__ e_ws, float* __restrict__ outzero) {
    int bid = blockIdx.x;
    int tid = threadIdx.x;

    if (bid < 4096) {
        // ---- key f32 -> bf16, blocked+swizzled ----
        const size_t nchunk = (size_t)B_ * T_ * KD_ / 8;
        size_t stride = (size_t)4096 * 256;
        for (size_t g = (size_t)bid * 256 + tid; g < nchunk; g += stride) {
            const float* p = key + g * 8;
            f32x4 f0 = *reinterpret_cast<const f32x4*>(p);
            f32x4 f1 = *reinterpret_cast<const f32x4*>(p + 4);
            s16x8 h;
            h[0] = f2bf(f0[0]); h[1] = f2bf(f0[1]); h[2] = f2bf(f0[2]); h[3] = f2bf(f0[3]);
            h[4] = f2bf(f1[0]); h[5] = f2bf(f1[1]); h[6] = f2bf(f1[2]); h[7] = f2bf(f1[3]);
            size_t m = g >> 7;
            int kc = (int)(g & 127);
            size_t mt = m >> 8;
            int r = (int)(m & 255);
            int ktile = kc >> 3;
            int sub = kc & 7;
            int c = (r << 3) | (sub ^ (r & 7));
            *reinterpret_cast<s16x8*>(keyB + (((mt * 16 + ktile) * 2048 + c) << 3)) = h;
        }
    } else if (bid < 5120) {
        // ---- weights -> bf16 blocked+swizzled WkTB ----
        __shared__ float tile[32][33];
        int wbid = bid - 4096;
        int n0 = (wbid & 31) * 32;
        int k0 = (wbid >> 5) * 32;
        int tx = tid & 31;
        int ty = tid >> 5;
        const float* src;
        int nloc;
        if (n0 < 512) { src = Wk_mono;  nloc = n0; }
        else          { src = Wk_chunk; nloc = n0 - 512; }
#pragma unroll
        for (int i = 0; i < 4; ++i) {
            int k = ty + i * 8;
            tile[k][tx] = src[(size_t)(k0 + k) * AD_ + nloc + tx];
        }
        __syncthreads();
        if (tid < 128) {
            int rl = tid >> 2;
            int sub2 = tid & 3;
            s16x8 h;
#pragma unroll
            for (int j = 0; j < 8; ++j)
                h[j] = f2bf(tile[sub2 * 8 + j][rl]);
            int n = n0 + rl;
            int nt = n >> 8;
            int rloc = n & 255;
            int ktile = k0 >> 6;
            int sub = ((k0 & 63) >> 3) + sub2;
            int c = (rloc << 3) | (sub ^ (rloc & 7));
            *reinterpret_cast<s16x8*>(WkTB + (((size_t)(nt * 16 + ktile) * 2048 + c) << 3)) = h;
        }
    } else if (bid < 5376) {
        // ---- qproj ----
        __shared__ float red[4][64];
        int qbid = bid - 5120;
        int b = qbid & 15;
        int mat = (qbid >> 4) & 1;
        int ac = qbid >> 5;
        const float* Wq = mat ? Wq_chunk : Wq_mono;
        const float* bb = mat ? b_chunk : b_mono;
        int al = tid & 63;
        int dg = tid >> 6;
        int a = ac * 64 + al;
        const float* q = query + b * KD_ + dg * 256;
        const float* wp = Wq + (size_t)(dg * 256) * AD_ + a;
        float s = 0.f;
#pragma unroll 4
        for (int d = 0; d < 256; ++d)
            s += q[d] * wp[(size_t)d * AD_];
        red[dg][al] = s;
        __syncthreads();
        if (dg == 0) {
            float t = red[0][al] + red[1][al] + red[2][al] + red[3][al];
            qb[(mat * B_ + b) * AD_ + a] = t + bb[a];
        }
    } else {
        // ---- zero e_ws (128 blocks x 4KB) then out (16 blocks x 4KB) ----
        int zbid = bid - 5376;
        f32x4 z = {0.f, 0.f, 0.f, 0.f};
        if (zbid < 128) {
            float* dst = e_ws + (size_t)zbid * 1024 + tid * 4;
            *reinterpret_cast<f32x4*>(dst) = z;
        } else {
            float* dst = outzero + (size_t)(zbid - 128) * 1024 + tid * 4;
            *reinterpret_cast<f32x4*>(dst) = z;
        }
    }
}

// ---------------- kernel 3: fused GEMM 256x256, BK=64, 8 waves, 8-phase counted-vmcnt ----------------
#define SBAR __builtin_amdgcn_sched_barrier(0)
#define BAR  do { SBAR; __builtin_amdgcn_s_barrier(); SBAR; } while (0)
#define VM6  asm volatile("s_waitcnt vmcnt(6)" ::: "memory")

#define STAGE_A(buf, kt, h) do { \
    const short* _g = aT + (((size_t)(kt) * 2048 + (h) * 1024) << 3); \
    gload16(_g + tid * 8,        &As[buf][(((h) * 1024 + wid * 64)) * 8]); \
    gload16(_g + (512 + tid) * 8, &As[buf][(((h) * 1024 + 512 + wid * 64)) * 8]); \
} while (0)

#define STAGE_B(buf, kt, h) do { \
    const short* _g = bT + (((size_t)(kt) * 2048 + (h) * 1024) << 3); \
    gload16(_g + tid * 8,        &Bs[buf][(((h) * 1024 + wid * 64)) * 8]); \
    gload16(_g + (512 + tid) * 8, &Bs[buf][(((h) * 1024 + 512 + wid * 64)) * 8]); \
} while (0)

#define DS_A(bb, mh) do { \
    _Pragma("unroll") \
    for (int _j = 0; _j < 4; ++_j) { \
        aR[_j][0] = *reinterpret_cast<const s16x8*>(&As[bb][aoff[(mh) * 4 + _j]]); \
        aR[_j][1] = *reinterpret_cast<const s16x8*>(&As[bb][aoff[(mh) * 4 + _j] ^ 32]); \
    } \
} while (0)

#define DS_B(bb, nh) do { \
    _Pragma("unroll") \
    for (int _j = 0; _j < 2; ++_j) { \
        bR[_j][0] = *reinterpret_cast<const s16x8*>(&Bs[bb][boff[(nh) * 2 + _j]]); \
        bR[_j][1] = *reinterpret_cast<const s16x8*>(&Bs[bb][boff[(nh) * 2 + _j] ^ 32]); \
    } \
} while (0)

#define MMA(mh, nh) do { \
    __builtin_amdgcn_s_setprio(1); \
    _Pragma("unroll") \
    for (int _j = 0; _j < 4; ++_j) \
    _Pragma("unroll") \
    for (int _n = 0; _n < 2; ++_n) { \
        acc[(mh) * 4 + _j][(nh) * 2 + _n] = __builtin_amdgcn_mfma_f32_16x16x32_bf16( \
            aR[_j][0], bR[_n][0], acc[(mh) * 4 + _j][(nh) * 2 + _n], 0, 0, 0); \
        acc[(mh) * 4 + _j][(nh) * 2 + _n] = __builtin_amdgcn_mfma_f32_16x16x32_bf16( \
            aR[_j][1], bR[_n][1], acc[(mh) * 4 + _j][(nh) * 2 + _n], 0, 0, 0); \
    } \
    __builtin_amdgcn_s_setprio(0); \
} while (0)

__global__ __launch_bounds__(512) void gemm_e_kernel(
    const short* __restrict__ keyB,
    const short* __restrict__ WkTB,
    const float* __restrict__ qb,
    const float* __restrict__ v_mono, const float* __restrict__ v_chunk,
    float* __restrict__ e_ws /* [2][B_*T_] */) {
    __shared__ short As[2][16384];   // 2 x 32 KB (256 rows x 64 K)
    __shared__ short Bs[2][16384];   // 2 x 32 KB
    int tid = threadIdx.x;
    int bid = blockIdx.x;
    int swz = (bid & 7) * 128 + (bid >> 3);   // XCD-aware (1024 % 8 == 0, bijective)
    int mt = swz >> 2;                        // 0..255
    int nt = swz & 3;                         // 0..3
    int mBase = mt * 256;
    int nBase = nt * 256;
    int lane = tid & 63;
    int wid = tid >> 6;                       // 0..7
    int wr = wid >> 2, wc = wid & 3;          // 2M x 4N waves; per-wave 128x64
    int col16 = lane & 15, g4 = lane >> 4;

    const short* aT = keyB + ((size_t)mt * 16 * 2048 << 3);
    const short* bT = WkTB + ((size_t)nt * 16 * 2048 << 3);

    // swizzled ds_read offsets (shorts); kk=1 -> ^32 (slot bit2 <-> sub bit2)
    int aoff[8], boff[4];
#pragma unroll
    for (int fi = 0; fi < 8; ++fi) {
        int row = wr * 128 + fi * 16 + col16;          // 0..255
        aoff[fi] = ((row << 3) | (g4 ^ (row & 7))) * 8;
    }
#pragma unroll
    for (int fj = 0; fj < 4; ++fj) {
        int col = wc * 64 + fj * 16 + col16;           // 0..255
        boff[fj] = ((col << 3) | (g4 ^ (col & 7))) * 8;
    }

    f32x4 acc[8][4];
#pragma unroll
    for (int i = 0; i < 8; ++i)
#pragma unroll
        for (int j = 0; j < 4; ++j) acc[i][j] = (f32x4){0.f, 0.f, 0.f, 0.f};

    s16x8 aR[4][2], bR[2][2];

    // prologue: 7 half-tiles: tile0 {A0,B0,B1,A1} -> buf0, tile1 {A0,B1,A1} -> buf1
    STAGE_A(0, 0, 0); STAGE_B(0, 0, 0); STAGE_B(0, 0, 1); STAGE_A(0, 0, 1);
    STAGE_A(1, 1, 0); STAGE_B(1, 1, 1); STAGE_A(1, 1, 1);
    VM6;   // tile0's 4 half-tiles landed; 3 in flight
    BAR;

    for (int it = 0; it < 8; ++it) {
        int t1 = 2 * it + 1;
        int t2 = 2 * it + 2 > 15 ? 15 : 2 * it + 2;
        int t3 = 2 * it + 3 > 15 ? 15 : 2 * it + 3;
        // P1: q(0,0) on buf0 | prefetch buf1.B0(t1)
        DS_A(0, 0); DS_B(0, 0);
        STAGE_B(1, t1, 0);
        BAR; MMA(0, 0); BAR;
        // P2: q(0,1) | prefetch buf0.A0(t2)
        DS_B(0, 1);
        STAGE_A(0, t2, 0);
        BAR; MMA(0, 1); BAR;
        // P3: q(1,1) | prefetch buf0.B1(t2)
        DS_A(0, 1);
        STAGE_B(0, t2, 1);
        BAR; MMA(1, 1); BAR;
        // P4: q(1,0) | prefetch buf0.A1(t2) | vmcnt(6): buf1(t1) complete
        DS_B(0, 0);
        STAGE_A(0, t2, 1);
        VM6;
        BAR; MMA(1, 0); BAR;
        // P5: q(0,0) on buf1 | prefetch buf0.B0(t2)
        DS_A(1, 0); DS_B(1, 0);
        STAGE_B(0, t2, 0);
        BAR; MMA(0, 0); BAR;
        // P6: q(0,1) | prefetch buf1.A0(t3)
        DS_B(1, 1);
        STAGE_A(1, t3, 0);
        BAR; MMA(0, 1); BAR;
        // P7: q(1,1) | prefetch buf1.B1(t3)
        DS_A(1, 1);
        STAGE_B(1, t3, 1);
        BAR; MMA(1, 1); BAR;
        // P8: q(1,0) | prefetch buf1.A1(t3) | vmcnt(6): buf0(t2) complete
        DS_B(1, 0);
        STAGE_A(1, t3, 1);
        VM6;
        BAR; MMA(1, 0); BAR;
    }

    asm volatile("s_waitcnt vmcnt(0)" ::: "memory");

    // epilogue: e[row] += sum_a v[a] * tanh(C[row][a] + qb[b][a])
    int bIdx = mBase >> 12;
    int matrix = nBase >> 9;            // nt 0,1 -> mono; 2,3 -> chunk
    int aBase = (nBase & 511) + wc * 64 + col16;
    const float* qbRow = qb + (matrix * B_ + bIdx) * AD_;
    const float* vv = matrix ? v_chunk : v_mono;
    float* eArr = e_ws + matrix * (B_ * T_);
    float qcol[4], vcol[4];
#pragma unroll
    for (int n = 0; n < 4; ++n) {
        int a = aBase + n * 16;
        qcol[n] = qbRow[a];
        vcol[n] = vv[a];
    }
#pragma unroll
    for (int fi = 0; fi < 8; ++fi) {
        float s0 = 0.f, s1 = 0.f, s2 = 0.f, s3 = 0.f;
#pragma unroll
        for (int n = 0; n < 4; ++n) {
            s0 += fast_tanh(acc[fi][n][0] + qcol[n]) * vcol[n];
            s1 += fast_tanh(acc[fi][n][1] + qcol[n]) * vcol[n];
            s2 += fast_tanh(acc[fi][n][2] + qcol[n]) * vcol[n];
            s3 += fast_tanh(acc[fi][n][3] + qcol[n]) * vcol[n];
        }
#pragma unroll
        for (int mask = 1; mask < 16; mask <<= 1) {
            s0 += __shfl_xor(s0, mask, 64);
            s1 += __shfl_xor(s1, mask, 64);
            s2 += __shfl_xor(s2, mask, 64);
            s3 += __shfl_xor(s3, mask, 64);
        }
        if (col16 == 0) {
            int rowB = mBase + wr * 128 + fi * 16 + g4 * 4;
            atomicAdd(&eArr[rowB + 0], s0);
            atomicAdd(&eArr[rowB + 1], s1);
            atomicAdd(&eArr[rowB + 2], s2);
            atomicAdd(&eArr[rowB + 3], s3);
        }
    }
}

// ---------------- kernel 4: per-batch scan -> aw, beta ----------------
__global__ __launch_bounds__(256) void scan_kernel(
    const float* __restrict__ e_ws,
    const float* __restrict__ noise,
    const float* __restrict__ r_mono, const float* __restrict__ r_chunk,
    float* __restrict__ aw_out, float* __restrict__ beta_out) {
    __shared__ float s_aw[T_];
    __shared__ float s_sexp[T_];
    __shared__ float s_ad[T_];
    __shared__ float s_w[4];
    int b = blockIdx.x;
    int tid = threadIdx.x;
    int lane = tid & 63;
    int wid4 = tid >> 6;
    int t0 = tid * 16;
    const float* em = e_ws + b * T_;
    const float* ec = e_ws + B_ * T_ + b * T_;
    const float* nz = noise + b * T_;
    float rm = r_mono[0], rc = r_chunk[0];

    float pv[16], lp[16];
    float run = 0.f;
#pragma unroll
    for (int j = 0; j < 16; ++j) {
        float x = em[t0 + j] + rm + nz[t0 + j];
        float p = 1.f / (1.f + expf(-x));
        pv[j] = p;
        float om = fminf(fmaxf(1.f - p, 1e-10f), 1.f);
        lp[j] = run;
        run += logf(om);
    }
    float x = run;
#pragma unroll
    for (int off = 1; off < 64; off <<= 1) {
        float y = __shfl_up(x, off, 64);
        if (lane >= off) x += y;
    }
    if (lane == 63) s_w[wid4] = x;
    __syncthreads();
    float wbase = 0.f;
#pragma unroll
    for (int i = 0; i < 3; ++i) if (i < wid4) wbase += s_w[i];
    float base = 1.f + (wbase + x - run);
#pragma unroll
    for (int j = 0; j < 16; ++j) {
        float aw = pv[j] * expf(base + lp[j]);
        s_aw[t0 + j] = aw;
        aw_out[b * T_ + t0 + j] = aw;
    }
    float evs[16];
    float lmax = -INFINITY;
#pragma unroll
    for (int j = 0; j < 16; ++j) {
        float v = ec[t0 + j] + rc;
        evs[j] = v;
        lmax = fmaxf(lmax, v);
    }
#pragma unroll
    for (int off = 1; off < 64; off <<= 1)
        lmax = fmaxf(lmax, __shfl_xor(lmax, off, 64));
    __syncthreads();
    if (lane == 0) s_w[wid4] = lmax;
    __syncthreads();
    float mx = fmaxf(fmaxf(s_w[0], s_w[1]), fmaxf(s_w[2], s_w[3]));
#pragma unroll
    for (int j = 0; j < 16; ++j)
        s_sexp[t0 + j] = fmaxf(expf(evs[j] - mx), 1e-5f);
    __syncthreads();
#pragma unroll
    for (int j = 0; j < 16; ++j) {
        int t = t0 + j;
        int lo = t - 7; if (lo < 0) lo = 0;
        float d = 0.f;
        for (int i = lo; i <= t; ++i) d += s_sexp[i];
        s_ad[t] = s_aw[t] / d;
    }
    __syncthreads();
#pragma unroll
    for (int j = 0; j < 16; ++j) {
        int t = t0 + j;
        int hi = t + 7; if (hi > T_ - 1) hi = T_ - 1;
        float m2 = 0.f;
        for (int i = t; i <= hi; ++i) m2 += s_ad[i];
        beta_out[b * T_ + t] = s_sexp[t] * m2;
    }
}

// ---------------- kernel 5: cv[b][d] = sum_t beta[b][t]*value[b][t][d] (256-row chunks, 256 blocks) ----------------
__global__ __launch_bounds__(256) void cv_kernel(
    const float* __restrict__ value,
    const float* __restrict__ beta,
    float* __restrict__ cv) {
    __shared__ float s_beta[256];
    int b = blockIdx.x;
    int tc = blockIdx.y;
    int tid = threadIdx.x;
    int t0 = tc * 256;
    s_beta[tid] = beta[b * T_ + t0 + tid];
    __syncthreads();
    int d0 = tid * 4;
    f32x4 acc = {0.f, 0.f, 0.f, 0.f};
    const float* vp = value + (size_t)(b * T_ + t0) * VD_ + d0;
#pragma unroll 4
    for (int i = 0; i < 256; ++i) {
        f32x4 v = *reinterpret_cast<const f32x4*>(vp + (size_t)i * VD_);
        float bt = s_beta[i];
        acc[0] += bt * v[0];
        acc[1] += bt * v[1];
        acc[2] += bt * v[2];
        acc[3] += bt * v[3];
    }
    atomicAdd(&cv[b * VD_ + d0 + 0], acc[0]);
    atomicAdd(&cv[b * VD_ + d0 + 1], acc[1]);
    atomicAdd(&cv[b * VD_ + d0 + 2], acc[2]);
    atomicAdd(&cv[b * VD_ + d0 + 3], acc[3]);
}

extern "C" void kernel_launch(void* const* d_in, const int* in_sizes, int n_in,
                              void* d_out, int out_size, void* d_ws, size_t ws_size,
                              hipStream_t stream) {
    const float* key      = (const float*)d_in[0];
    const float* value    = (const float*)d_in[1];
    const float* query    = (const float*)d_in[2];
    const float* noise    = (const float*)d_in[3];
    const float* Wk_mono  = (const float*)d_in[4];
    const float* b_mono   = (const float*)d_in[5];
    const float* Wq_mono  = (const float*)d_in[6];
    const float* Wk_chunk = (const float*)d_in[7];
    const float* b_chunk  = (const float*)d_in[8];
    const float* Wq_chunk = (const float*)d_in[9];
    const float* r_mono   = (const float*)d_in[10];
    const float* r_chunk  = (const float*)d_in[11];
    const float* v_mono   = (const float*)d_in[12];
    const float* v_chunk  = (const float*)d_in[13];
    float* out = (float*)d_out;   // [0,16384): cv ; [16384, 81920): aw

    char* ws = (char*)d_ws;
    size_t off = 0;
    float* e_ws = (float*)(ws + off); off += 2 * B_ * T_ * sizeof(float);      // 512 KB
    float* qb   = (float*)(ws + off); off += 2 * B_ * AD_ * sizeof(float);     // 64 KB
    short* WkTB = (short*)(ws + off); off += (size_t)KD_ * KD_ * 2;            // 2 MB
    float* beta = (float*)(ws + off); off += B_ * T_ * sizeof(float);          // 256 KB
    short* keyB = (short*)(ws + off);                                          // 134 MB

    prep_kernel<<<5520, 256, 0, stream>>>(key, keyB, Wk_mono, Wk_chunk, WkTB,
                                          query, Wq_mono, b_mono, Wq_chunk, b_chunk, qb,
                                          e_ws, out);
    gemm_e_kernel<<<1024, 512, 0, stream>>>(keyB, WkTB, qb, v_mono, v_chunk, e_ws);
    scan_kernel<<<16, 256, 0, stream>>>(e_ws, noise, r_mono, r_chunk, out + B_ * VD_, beta);
    cv_kernel<<<dim3(16, 16), 256, 0, stream>>>(value, beta, out);
}